// Round 4
// baseline (1718.216 us; speedup 1.0000x reference)
//
#include <hip/hip_runtime.h>
#include <hip/hip_bf16.h>
#include <stdint.h>

typedef __bf16 bf16x8 __attribute__((ext_vector_type(8)));
typedef float  f32x4  __attribute__((ext_vector_type(4)));
typedef unsigned short ushort_t;

#define BATCH 16384
#define HID   1024
#define KK    16
#define NKB   32      // 32 K-blocks of 32 f32 cols
#define BM    256
#define BN    256
#define BUFS  32768   // ushorts per LDS buffer (A 16384 | W 16384)
#define LDSW_OFF 16384

// ---- fp32 -> bf16 hi/lo split (RNE) ----
__device__ __forceinline__ unsigned short bf16_rne(float x) {
    uint32_t u = __float_as_uint(x);
    uint32_t r = (u + 0x7fffu + ((u >> 16) & 1u)) >> 16;
    return (unsigned short)r;
}
__device__ __forceinline__ void split2(float x, unsigned short& h, unsigned short& l) {
    h = bf16_rne(x);
    float hf = __uint_as_float(((uint32_t)h) << 16);
    l = bf16_rne(x - hf);   // x - hf exact in f32
}

// ---- split A -> Acomb[kb][b][8 chunks of 8 ushorts], chunks PRE-SWIZZLED by (b&7) ----
__global__ __launch_bounds__(256) void k_split_a(const float* __restrict__ A,
                                                 ushort_t* __restrict__ Acomb) {
    uint32_t q   = blockIdx.x * 256u + threadIdx.x;   // 2,097,152 threads
    uint32_t b   = q >> 7;
    uint32_t rem = q & 127u;
    uint32_t kb  = rem >> 2;
    uint32_t cq  = rem & 3u;
    const float* src = A + (size_t)b * HID + kb * 32 + cq * 8;
    float4 v0 = *(const float4*)src;
    float4 v1 = *(const float4*)(src + 4);
    ushort_t h[8], l[8];
    split2(v0.x, h[0], l[0]); split2(v0.y, h[1], l[1]);
    split2(v0.z, h[2], l[2]); split2(v0.w, h[3], l[3]);
    split2(v1.x, h[4], l[4]); split2(v1.y, h[5], l[5]);
    split2(v1.z, h[6], l[6]); split2(v1.w, h[7], l[7]);
    ushort_t* row = Acomb + ((size_t)kb * BATCH + b) * 64;
    uint32_t sw = b & 7u;
    *(uint4*)(row + ((cq      ) ^ sw) * 8) = *(uint4*)h;
    *(uint4*)(row + ((cq + 4u) ^ sw) * 8) = *(uint4*)l;
}

// ---- split+transpose W -> Wcomb[i][kb][d][8 chunks], chunks PRE-SWIZZLED by (d&7) ----
__global__ __launch_bounds__(256) void k_split_w(const float* __restrict__ W,
                                                 ushort_t* __restrict__ Wcomb) {
    int bx = blockIdx.x;            // 16*32*16 = 8192 blocks
    int i  = bx >> 9;
    int kb = (bx >> 4) & 31;
    int dt = bx & 15;
    __shared__ float lds[32][65];
    const float* src = W + ((size_t)i * HID + (size_t)kb * 32) * HID + dt * 64;
    int t = threadIdx.x;
    #pragma unroll
    for (int rep = 0; rep < 8; ++rep) {
        int lin = rep * 256 + t;            // 0..2047
        int hl = lin >> 6, dl = lin & 63;
        lds[hl][dl] = src[(size_t)hl * HID + dl];
    }
    __syncthreads();
    #pragma unroll
    for (int rep = 0; rep < 2; ++rep) {
        int cid = rep * 256 + t;            // 0..511 chunks of 8 ushorts
        int dl = cid >> 3, qq = cid & 7;
        ushort_t outv[8];
        #pragma unroll
        for (int j = 0; j < 8; ++j) {
            int col = qq * 8 + j;           // col<32: hi(h=col); else lo(h=col-32)
            float x = (col < 32) ? lds[col][dl] : lds[col - 32][dl];
            unsigned short h, l; split2(x, h, l);
            outv[j] = (col < 32) ? h : l;
        }
        *(uint4*)(Wcomb + ((((size_t)i * NKB + kb) * HID) + dt * 64 + dl) * 64
                  + (qq ^ (dl & 7)) * 8) = *(uint4*)outv;
    }
}

// ---- main bilinear MFMA kernel: 256x256 tile, 8 waves, 2-barrier/tile + counted vmcnt ----
#define GLL(gsrc, dstIdx) \
    __builtin_amdgcn_global_load_lds((const __attribute__((address_space(1))) void*)(gsrc), \
        (__attribute__((address_space(3))) void*)(&smem[(dstIdx)]), 16, 0, 0)

__global__ __launch_bounds__(512, 2) void k_gemm(const ushort_t* __restrict__ Acomb,
                                                 const ushort_t* __restrict__ Wcomb,
                                                 const float* __restrict__ B,
                                                 float* __restrict__ score) {
    __shared__ __align__(16) ushort_t smem[2 * BUFS];   // 128 KiB
    const int tid  = threadIdx.x;
    const int lane = tid & 63;
    const int wave = tid >> 6;
    const int wm = wave >> 2, wn = wave & 3;
    const int l15 = lane & 15, l4 = lane >> 4;
    const int brow = blockIdx.x * BM;
    const int dcol = blockIdx.y * BN;
    const int i    = blockIdx.z;

    f32x4 acc[8][4];
    #pragma unroll
    for (int m = 0; m < 8; ++m)
        #pragma unroll
        for (int n = 0; n < 4; ++n)
            acc[m][n] = (f32x4){0.f, 0.f, 0.f, 0.f};

    // ds-read fragment bases (ushort units); swizzle: chunk ^= (row&7)
    const int csw_hi = ((l4    ) ^ (l15 & 7)) * 8;
    const int csw_lo = ((l4 + 4) ^ (l15 & 7)) * 8;
    const int aoff_hi = (wm * 128 + l15) * 64 + csw_hi;             // + m*1024 + cb
    const int aoff_lo = (wm * 128 + l15) * 64 + csw_lo;
    const int woff_hi = LDSW_OFF + (wn * 64 + l15) * 64 + csw_hi;   // + n*1024 + cb
    const int woff_lo = LDSW_OFF + (wn * 64 + l15) * 64 + csw_lo;

    // staging bases: per-thread global (pre-swizzled layout -> LDS dest fully linear)
    const ushort_t* gA0 = Acomb + ((size_t)brow + wave * 16) * 64 + lane * 8;
    const ushort_t* gW0 = Wcomb + ((size_t)i * NKB * HID + dcol + wave * 16) * 64 + lane * 8;
    const int sdst = wave * 1024;    // wave-uniform LDS dest (ushorts)

#define STAGE_A(c, t1, h) do { \
    const ushort_t* g_ = gA0 + ((size_t)(t1) * BATCH + (h) * 128) * 64; \
    GLL(g_,       (c) * BUFS + (h) * 8192 + sdst); \
    GLL(g_ + 512, (c) * BUFS + (h) * 8192 + sdst + 512); \
  } while (0)
#define STAGE_W(c, t1, h) do { \
    const ushort_t* g_ = gW0 + ((size_t)(t1) * HID + (h) * 128) * 64; \
    GLL(g_,       (c) * BUFS + LDSW_OFF + (h) * 8192 + sdst); \
    GLL(g_ + 512, (c) * BUFS + LDSW_OFF + (h) * 8192 + sdst + 512); \
  } while (0)
#define STAGE_TILE(c, t1) do { \
    STAGE_A(c, t1, 0); STAGE_A(c, t1, 1); \
    STAGE_W(c, t1, 0); STAGE_W(c, t1, 1); \
  } while (0)

    bf16x8 ah[4], al[4], wh[4], wl[4];
#define RD_W(n, cb) do { \
    wh[n] = *(const bf16x8*)(&smem[(cb) + woff_hi + (n) * 1024]); \
    wl[n] = *(const bf16x8*)(&smem[(cb) + woff_lo + (n) * 1024]); } while (0)
#define RD_A(m, slot, cb) do { \
    ah[slot] = *(const bf16x8*)(&smem[(cb) + aoff_hi + (m) * 1024]); \
    al[slot] = *(const bf16x8*)(&smem[(cb) + aoff_lo + (m) * 1024]); } while (0)

#define MFMA_Q(MB, NB) do { \
    __builtin_amdgcn_s_setprio(1); \
    _Pragma("unroll") \
    for (int mm = 0; mm < 4; ++mm) { \
      _Pragma("unroll") \
      for (int nn = 0; nn < 2; ++nn) \
        acc[(MB)+mm][(NB)+nn] = __builtin_amdgcn_mfma_f32_16x16x32_bf16(ah[mm], wh[(NB)+nn], acc[(MB)+mm][(NB)+nn], 0, 0, 0); } \
    _Pragma("unroll") \
    for (int mm = 0; mm < 4; ++mm) { \
      _Pragma("unroll") \
      for (int nn = 0; nn < 2; ++nn) \
        acc[(MB)+mm][(NB)+nn] = __builtin_amdgcn_mfma_f32_16x16x32_bf16(ah[mm], wl[(NB)+nn], acc[(MB)+mm][(NB)+nn], 0, 0, 0); } \
    _Pragma("unroll") \
    for (int mm = 0; mm < 4; ++mm) { \
      _Pragma("unroll") \
      for (int nn = 0; nn < 2; ++nn) \
        acc[(MB)+mm][(NB)+nn] = __builtin_amdgcn_mfma_f32_16x16x32_bf16(al[mm], wh[(NB)+nn], acc[(MB)+mm][(NB)+nn], 0, 0, 0); } \
    __builtin_amdgcn_s_setprio(0); \
  } while (0)

// whole K-tile compute: no internal barriers (all reads hit an already-complete buffer)
#define TILE_COMPUTE(cb) do { \
    RD_W(0, cb); RD_W(1, cb); \
    RD_A(0, 0, cb); RD_A(1, 1, cb); RD_A(2, 2, cb); RD_A(3, 3, cb); \
    MFMA_Q(0, 0); \
    RD_W(2, cb); RD_W(3, cb); \
    MFMA_Q(0, 2); \
    RD_A(4, 0, cb); RD_A(5, 1, cb); RD_A(6, 2, cb); RD_A(7, 3, cb); \
    MFMA_Q(4, 0); \
    MFMA_Q(4, 2); \
  } while (0)

// boundary: reads-done barrier, stage t+2 into the buffer just freed, counted-vmcnt barrier
#define TILE_BOUNDARY(c, t2) do { \
    asm volatile("s_waitcnt lgkmcnt(0)" ::: "memory"); \
    __builtin_amdgcn_s_barrier(); \
    __builtin_amdgcn_sched_barrier(0); \
    if ((t2) < NKB) { \
        STAGE_TILE(c, t2); \
        asm volatile("s_waitcnt vmcnt(8)" ::: "memory"); \
    } else { \
        asm volatile("s_waitcnt vmcnt(0)" ::: "memory"); \
    } \
    __builtin_amdgcn_s_barrier(); \
    __builtin_amdgcn_sched_barrier(0); \
  } while (0)

    // prologue: stage tiles 0 and 1; wait tile0 resident (tile1 stays in flight)
    STAGE_TILE(0, 0);
    STAGE_TILE(1, 1);
    asm volatile("s_waitcnt vmcnt(8)" ::: "memory");
    __builtin_amdgcn_s_barrier();
    __builtin_amdgcn_sched_barrier(0);

    #pragma unroll 1
    for (int t = 0; t < NKB; t += 2) {
        TILE_COMPUTE(0);
        TILE_BOUNDARY(0, t + 2);
        TILE_COMPUTE(BUFS);
        TILE_BOUNDARY(1, t + 3);
    }

    // epilogue: multiply by B, reduce over d (cols), atomicAdd into score[b,i]
    #pragma unroll
    for (int m = 0; m < 8; ++m) {
        #pragma unroll
        for (int r = 0; r < 4; ++r) {
            int row = brow + wm * 128 + m * 16 + l4 * 4 + r;   // global b
            const float* Brow = B + (size_t)row * HID + dcol + wn * 64 + l15;
            float s = acc[m][0][r] * Brow[0]
                    + acc[m][1][r] * Brow[16]
                    + acc[m][2][r] * Brow[32]
                    + acc[m][3][r] * Brow[48];
            s += __shfl_xor(s, 1);
            s += __shfl_xor(s, 2);
            s += __shfl_xor(s, 4);
            s += __shfl_xor(s, 8);
            if (l15 == 0) atomicAdd(&score[(size_t)row * KK + i], s);
        }
    }
}

// ---- linear term ----
__global__ __launch_bounds__(256) void k_linear(const float* __restrict__ A,
                                                const float* __restrict__ B,
                                                const float* __restrict__ Vw,
                                                const float* __restrict__ Vb,
                                                float* __restrict__ lin) {
    __shared__ float4 sA[128][9];
    __shared__ float4 sB[128][9];
    __shared__ float4 sVa[16][9];
    __shared__ float4 sVb[16][9];
    const int t = threadIdx.x;
    const int brow = blockIdx.x * 128;
    const int b_loc = t >> 1;
    const int ihalf = t & 1;
    float acc8[8] = {0.f, 0.f, 0.f, 0.f, 0.f, 0.f, 0.f, 0.f};

    for (int hc = 0; hc < HID; hc += 32) {
        __syncthreads();
        #pragma unroll
        for (int rep = 0; rep < 4; ++rep) {
            int idx = rep * 256 + t;
            int bl = idx >> 3, h4 = idx & 7;
            sA[bl][h4] = *(const float4*)(A + (size_t)(brow + bl) * HID + hc + h4 * 4);
            sB[bl][h4] = *(const float4*)(B + (size_t)(brow + bl) * HID + hc + h4 * 4);
        }
        if (t < 128) {
            int ii = t >> 3, h4 = t & 7;
            sVa[ii][h4] = *(const float4*)(Vw + (size_t)ii * 2048 + hc + h4 * 4);
        } else {
            int tt = t - 128;
            int ii = tt >> 3, h4 = tt & 7;
            sVb[ii][h4] = *(const float4*)(Vw + (size_t)ii * 2048 + 1024 + hc + h4 * 4);
        }
        __syncthreads();
        #pragma unroll
        for (int h4 = 0; h4 < 8; ++h4) {
            float4 a4 = sA[b_loc][h4];
            float4 b4 = sB[b_loc][h4];
            #pragma unroll
            for (int ii = 0; ii < 8; ++ii) {
                int iG = ihalf * 8 + ii;
                float4 va = sVa[iG][h4], vb = sVb[iG][h4];
                acc8[ii] += a4.x * va.x + a4.y * va.y + a4.z * va.z + a4.w * va.w
                          + b4.x * vb.x + b4.y * vb.y + b4.z * vb.z + b4.w * vb.w;
            }
        }
    }
    #pragma unroll
    for (int ii = 0; ii < 8; ++ii) {
        int iG = ihalf * 8 + ii;
        lin[(size_t)(brow + b_loc) * KK + iG] = acc8[ii] + Vb[iG];
    }
}

// ---- finalize ----
__global__ __launch_bounds__(256) void k_final(const float* __restrict__ score,
                                               const float* __restrict__ lin,
                                               const float* __restrict__ out_w,
                                               const float* __restrict__ out_b,
                                               float* __restrict__ out) {
    int b = blockIdx.x * 256 + threadIdx.x;
    float o = out_b[0];
    #pragma unroll
    for (int i = 0; i < KK; ++i)
        o += out_w[i] * tanhf(score[(size_t)b * KK + i] + lin[(size_t)b * KK + i]);
    out[b] = o;
}

extern "C" void kernel_launch(void* const* d_in, const int* in_sizes, int n_in,
                              void* d_out, int out_size, void* d_ws, size_t ws_size,
                              hipStream_t stream) {
    (void)in_sizes; (void)n_in; (void)out_size; (void)ws_size;
    const float* A     = (const float*)d_in[0];
    const float* B     = (const float*)d_in[1];
    const float* W     = (const float*)d_in[2];
    const float* Vw    = (const float*)d_in[3];
    const float* Vb    = (const float*)d_in[4];
    const float* out_w = (const float*)d_in[5];
    const float* out_b = (const float*)d_in[6];
    float* out = (float*)d_out;

    // workspace: Acomb 64MiB | Wcomb 64MiB | score 1MiB | lin 1MiB
    ushort_t* Acomb = (ushort_t*)d_ws;
    ushort_t* Wcomb = Acomb + (size_t)NKB * BATCH * 64;
    float* score = (float*)(Wcomb + (size_t)KK * NKB * HID * 64);
    float* lin   = score + (size_t)BATCH * KK;

    hipMemsetAsync(score, 0, (size_t)BATCH * KK * sizeof(float), stream);
    k_split_a<<<dim3(8192), dim3(256), 0, stream>>>(A, Acomb);
    k_split_w<<<dim3(8192), dim3(256), 0, stream>>>(W, Wcomb);
    k_gemm<<<dim3(BATCH / BM, HID / BN, KK), dim3(512), 0, stream>>>(Acomb, Wcomb, B, score);
    k_linear<<<dim3(BATCH / 128), dim3(256), 0, stream>>>(A, B, Vw, Vb, lin);
    k_final<<<dim3(BATCH / 256), dim3(256), 0, stream>>>(score, lin, out_w, out_b, out);
}